// Round 4
// baseline (1163.979 us; speedup 1.0000x reference)
//
#include <hip/hip_runtime.h>
#include <hip/hip_cooperative_groups.h>
#include <math.h>

namespace cg = cooperative_groups;

// TreeLSTM, complete binary tree N = 2^15-1 (implicit: children(i)=2i+1,2i+2).
// Round 4: (1) bulk_xw XCD-swizzled so the 8 channel-slab blocks of one m-tile
// share an XCD L2 (x fetched once); (2) all 14 internal levels fused into one
// cooperative kernel with grid.sync between levels, W_hh slab resident in LDS
// across the whole level loop (64KB) so the serial k-loop only stages A;
// (3) gx stored [node][CH][4q] for one 8B epilogue load.

#define N_NODES 32767
#define N_LEAF0 16383
#define IN_C    512
#define H_C     256

typedef __bf16 bf16x8 __attribute__((ext_vector_type(8)));
typedef __bf16 bf16x4 __attribute__((ext_vector_type(4)));
typedef float  f32x4  __attribute__((ext_vector_type(4)));

__device__ __forceinline__ void gload_lds16(const void* g, void* l) {
    __builtin_amdgcn_global_load_lds(
        (const __attribute__((address_space(1))) unsigned int*)g,
        (__attribute__((address_space(3))) unsigned int*)l,
        16, 0, 0);
}

__device__ __forceinline__ float fast_rcp(float x) { return __builtin_amdgcn_rcpf(x); }
__device__ __forceinline__ float sigm(float x)     { return fast_rcp(1.f + __expf(-x)); }
__device__ __forceinline__ float tanh_fast(float x){ return 2.f * fast_rcp(1.f + __expf(-2.f * x)) - 1.f; }

// ---- fp32 -> bf16 converter (weights only) ----
__global__ __launch_bounds__(256)
void conv_bf16_kernel(const float* __restrict__ src, __bf16* __restrict__ dst, int n8)
{
    const int i = blockIdx.x * 256 + threadIdx.x;
    if (i < n8) {
        const float4* s4 = (const float4*)src;
        const float4 a = s4[2 * i];
        const float4 b = s4[2 * i + 1];
        bf16x8 o;
        o[0] = (__bf16)a.x; o[1] = (__bf16)a.y; o[2] = (__bf16)a.z; o[3] = (__bf16)a.w;
        o[4] = (__bf16)b.x; o[5] = (__bf16)b.y; o[6] = (__bf16)b.z; o[7] = (__bf16)b.w;
        *(bf16x8*)(dst + 8 * i) = o;
    }
}

// ---- bulk: acc = x @ W_ih^T for ALL nodes. Leaves: full cell. Internal: gx.
// grid = 2048 linear; cb = bx>>8 (slab), mt = bx&255 (m-tile) => bx%8 == mt%8,
// all 8 slabs of an m-tile land on one XCD (round-robin heuristic).
__global__ __launch_bounds__(256)
void bulk_xw(const float* __restrict__ x,
             const __bf16* __restrict__ wih,
             const float* __restrict__ b_ih,
             const float* __restrict__ b_hh,
             __bf16* __restrict__ hb,
             float* __restrict__ c,
             __bf16* __restrict__ gx)
{
    __shared__ __bf16 As[128 * 32];
    __shared__ __bf16 Bs[128 * 32];

    const int t    = threadIdx.x;
    const int lane = t & 63;
    const int wv   = t >> 6;
    const int wm   = wv >> 1;
    const int wn   = wv & 1;
    const int quad = lane >> 4;
    const int l15  = lane & 15;
    const int bx   = blockIdx.x;
    const int cb   = bx >> 8;
    const int m0   = (bx & 255) * 128;

    f32x4 acc[4][4];
#pragma unroll
    for (int mi = 0; mi < 4; ++mi)
#pragma unroll
        for (int ni = 0; ni < 4; ++ni) acc[mi][ni] = (f32x4)0.f;

    for (int k0 = 0; k0 < IN_C; k0 += 32) {
#pragma unroll
        for (int e = 0; e < 2; ++e) {
            const int chunk = wv * 2 + e;
            const int nl    = chunk * 16 + (lane >> 2);
            const int q     = (nl >> 4) & 3;
            const int cc    = (nl & 15) + ((nl >> 6) << 4);
            const int grow  = q * H_C + cb * 32 + cc;
            const void* g = (const char*)(wih + grow * IN_C + k0) + (lane & 3) * 16;
            gload_lds16(g, (char*)Bs + chunk * 1024);
        }
        {
            const int row  = t >> 1;
            const int kh   = (t & 1) * 16;
            const int node = min(m0 + row, N_NODES - 1);
            const float4* xs = (const float4*)(x + (size_t)node * IN_C + k0 + kh);
            const float4 v0 = xs[0], v1 = xs[1], v2 = xs[2], v3 = xs[3];
            bf16x8 o0, o1;
            o0[0] = (__bf16)v0.x; o0[1] = (__bf16)v0.y; o0[2] = (__bf16)v0.z; o0[3] = (__bf16)v0.w;
            o0[4] = (__bf16)v1.x; o0[5] = (__bf16)v1.y; o0[6] = (__bf16)v1.z; o0[7] = (__bf16)v1.w;
            o1[0] = (__bf16)v2.x; o1[1] = (__bf16)v2.y; o1[2] = (__bf16)v2.z; o1[3] = (__bf16)v2.w;
            o1[4] = (__bf16)v3.x; o1[5] = (__bf16)v3.y; o1[6] = (__bf16)v3.z; o1[7] = (__bf16)v3.w;
            bf16x8* dst = (bf16x8*)(As + row * 32 + kh);
            dst[0] = o0;
            dst[1] = o1;
        }
        __syncthreads();
        bf16x8 af[4], bfr[4];
#pragma unroll
        for (int mi = 0; mi < 4; ++mi)
            af[mi] = *(const bf16x8*)(As + (wm * 64 + mi * 16 + l15) * 32 + quad * 8);
#pragma unroll
        for (int ni = 0; ni < 4; ++ni)
            bfr[ni] = *(const bf16x8*)(Bs + (wn * 64 + ni * 16 + l15) * 32 + quad * 8);
#pragma unroll
        for (int mi = 0; mi < 4; ++mi)
#pragma unroll
            for (int ni = 0; ni < 4; ++ni)
                acc[mi][ni] = __builtin_amdgcn_mfma_f32_16x16x32_bf16(
                    af[mi], bfr[ni], acc[mi][ni], 0, 0, 0);
        __syncthreads();
    }

    const int CH = cb * 32 + wn * 16 + l15;
    float bs[4];
#pragma unroll
    for (int q = 0; q < 4; ++q) bs[q] = b_ih[q * H_C + CH] + b_hh[q * H_C + CH];

#pragma unroll
    for (int mi = 0; mi < 4; ++mi) {
#pragma unroll
        for (int r = 0; r < 4; ++r) {
            const int m = m0 + wm * 64 + mi * 16 + quad * 4 + r;
            if (m >= N_NODES) continue;
            if (m >= N_LEAF0) {
                const float gi = sigm(acc[mi][0][r] + bs[0]);
                const float gg = tanh_fast(acc[mi][2][r] + bs[2]);
                const float go = sigm(acc[mi][3][r] + bs[3]);
                const float cn = gi * gg;
                const float hn = go * tanh_fast(cn);
                c[(size_t)m * H_C + CH] = cn;
                hb[(size_t)m * H_C + CH] = (__bf16)hn;
            } else {
                bf16x4 g4;
#pragma unroll
                for (int q = 0; q < 4; ++q) g4[q] = (__bf16)acc[mi][q][r];
                *(bf16x4*)(gx + (size_t)m * 1024 + CH * 4) = g4;
            }
        }
    }
}

// ---- fused internal levels 13..0, cooperative (512 blocks, grid.sync). ----
// bx = cb*nm + mt per level (nm = m-tiles). W_hh slab staged in LDS ONCE.
__global__ __launch_bounds__(256)
void levels_fused(const __bf16* __restrict__ whh,
                  const float* __restrict__ b_ih,
                  const float* __restrict__ b_hh,
                  const __bf16* __restrict__ gx,
                  __bf16* __restrict__ hb,
                  float* __restrict__ c)
{
    cg::grid_group gg_ = cg::this_grid();

    __shared__ __bf16 Bfull[8 * 128 * 32];   // 64 KB: whole K=256 W_hh slab
    __shared__ __bf16 As[128 * 32];          // 8 KB

    const int t    = threadIdx.x;
    const int lane = t & 63;
    const int wv   = t >> 6;
    const int wm   = wv >> 1;
    const int wn   = wv & 1;
    const int quad = lane >> 4;
    const int l15  = lane & 15;
    const int bx   = blockIdx.x;

    // every block stages the B slab for ITS cb of the largest level mapping; but
    // cb depends on level mapping -> cb is bx>>6 only for d=13. To keep one
    // resident slab, fix slab ownership: cb0 = bx & 7 is NOT constant across
    // levels in the bx=cb*nm+mt mapping. Instead use mapping cb = bx % 8,
    // mt = bx >> 3  (constant slab per block across ALL levels; XCD sharing of
    // children reads is sacrificed, W reuse + one-time staging is kept).
    const int cb = bx & 7;
    const int mt = bx >> 3;     // 0..63

    // ---- stage W_hh slab once: 8 k-chunks x (128 rows x 32 k) ----
#pragma unroll
    for (int kc = 0; kc < 8; ++kc) {
#pragma unroll
        for (int e = 0; e < 2; ++e) {
            const int chunk = wv * 2 + e;
            const int nl    = chunk * 16 + (lane >> 2);
            const int q     = (nl >> 4) & 3;
            const int cc    = (nl & 15) + ((nl >> 6) << 4);
            const int grow  = q * H_C + cb * 32 + cc;
            const void* g = (const char*)(whh + grow * H_C + kc * 32) + (lane & 3) * 16;
            gload_lds16(g, (char*)Bfull + kc * 8192 + chunk * 1024);
        }
    }
    __syncthreads();

    const int CH = cb * 32 + wn * 16 + l15;
    const float bs0 = b_ih[0 * H_C + CH] + b_hh[0 * H_C + CH];
    const float bs1 = b_ih[1 * H_C + CH] + b_hh[1 * H_C + CH];
    const float bs2 = b_ih[2 * H_C + CH] + b_hh[2 * H_C + CH];
    const float bs3 = b_ih[3 * H_C + CH] + b_hh[3 * H_C + CH];

    // pre-load B fragments? (they're reused every level) — 8 kc x 4 ni x 8 regs
    // = 256 VGPRs: too many. Read from LDS per level instead.

    for (int d = 13; d >= 0; --d) {
        const int n  = 1 << d;
        const int lo = n - 1;
        const int nm = (d > 7) ? (1 << (d - 7)) : 1;   // m-tiles of 128
        if (mt < nm) {
            const int m0 = mt * 128;

            f32x4 acc[4][4];
#pragma unroll
            for (int mi = 0; mi < 4; ++mi)
#pragma unroll
                for (int ni = 0; ni < 4; ++ni) acc[mi][ni] = (f32x4)0.f;

            for (int kc = 0; kc < 8; ++kc) {
                // stage A: mean of children h (rows beyond n read stale data,
                // results discarded row-locally in the epilogue)
                {
                    const int row  = t >> 1;
                    const int kh   = (t & 1) * 16;
                    const int node = lo + m0 + row;
                    const int k2   = kc * 32 + kh;
                    const bf16x8* hl = (const bf16x8*)(hb + (size_t)(2 * node + 1) * H_C + k2);
                    const bf16x8* hr = (const bf16x8*)(hb + (size_t)(2 * node + 2) * H_C + k2);
                    const bf16x8 a0 = hl[0], a1 = hl[1], b0 = hr[0], b1 = hr[1];
                    bf16x8 o0, o1;
#pragma unroll
                    for (int j = 0; j < 8; ++j) {
                        o0[j] = (__bf16)(0.5f * ((float)a0[j] + (float)b0[j]));
                        o1[j] = (__bf16)(0.5f * ((float)a1[j] + (float)b1[j]));
                    }
                    bf16x8* dst = (bf16x8*)(As + row * 32 + kh);
                    dst[0] = o0;
                    dst[1] = o1;
                }
                __syncthreads();
                bf16x8 af[4], bfr[4];
#pragma unroll
                for (int mi = 0; mi < 4; ++mi)
                    af[mi] = *(const bf16x8*)(As + (wm * 64 + mi * 16 + l15) * 32 + quad * 8);
#pragma unroll
                for (int ni = 0; ni < 4; ++ni)
                    bfr[ni] = *(const bf16x8*)(Bfull + kc * 4096 +
                                               (wn * 64 + ni * 16 + l15) * 32 + quad * 8);
#pragma unroll
                for (int mi = 0; mi < 4; ++mi)
#pragma unroll
                    for (int ni = 0; ni < 4; ++ni)
                        acc[mi][ni] = __builtin_amdgcn_mfma_f32_16x16x32_bf16(
                            af[mi], bfr[ni], acc[mi][ni], 0, 0, 0);
                __syncthreads();
            }

            // epilogue
#pragma unroll
            for (int mi = 0; mi < 4; ++mi) {
#pragma unroll
                for (int r = 0; r < 4; ++r) {
                    const int m = m0 + wm * 64 + mi * 16 + quad * 4 + r;
                    if (m < n) {
                        const int node = lo + m;
                        const bf16x4 g4 = *(const bf16x4*)(gx + (size_t)node * 1024 + CH * 4);
                        const float gi = sigm(acc[mi][0][r] + (float)g4[0] + bs0);
                        const float gf = sigm(acc[mi][1][r] + (float)g4[1] + bs1);
                        const float gt = tanh_fast(acc[mi][2][r] + (float)g4[2] + bs2);
                        const float go = sigm(acc[mi][3][r] + (float)g4[3] + bs3);
                        const float mc = 0.5f * (c[(size_t)(2 * node + 1) * H_C + CH] +
                                                 c[(size_t)(2 * node + 2) * H_C + CH]);
                        const float cn = gf * mc + gi * gt;
                        const float hn = go * tanh_fast(cn);
                        c[(size_t)node * H_C + CH] = cn;
                        hb[(size_t)node * H_C + CH] = (__bf16)hn;
                    }
                }
            }
        }
        gg_.sync();
    }
}

// ---- pooled mean + fc ----
__global__ __launch_bounds__(256)
void reduce_rows(const __bf16* __restrict__ hb, float* __restrict__ part)
{
    const int tcol = threadIdx.x;
    const int b = blockIdx.x;
    float s = 0.f;
    for (int r = 0; r < 128; ++r) {
        const int row = b * 128 + r;
        if (row < N_NODES) s += (float)hb[(size_t)row * H_C + tcol];
    }
    part[b * H_C + tcol] = s;
}

__global__ __launch_bounds__(256)
void reduce_final(const float* __restrict__ part,
                  const float* __restrict__ W_fc,
                  const float* __restrict__ b_fc,
                  float* __restrict__ out)
{
    __shared__ float sm[256];
    const int t = threadIdx.x;
    float s = 0.f;
    for (int j = 0; j < 256; ++j) s += part[j * H_C + t];
    s = s * (1.0f / (float)N_NODES) * W_fc[t];
    sm[t] = s;
    __syncthreads();
    for (int st = 128; st > 0; st >>= 1) {
        if (t < st) sm[t] += sm[t + st];
        __syncthreads();
    }
    if (t == 0) out[0] = sm[0] + b_fc[0];
}

extern "C" void kernel_launch(void* const* d_in, const int* in_sizes, int n_in,
                              void* d_out, int out_size, void* d_ws, size_t ws_size,
                              hipStream_t stream)
{
    const float* x    = (const float*)d_in[0];
    const float* W_ih = (const float*)d_in[2];
    const float* W_hh = (const float*)d_in[3];
    const float* b_ih = (const float*)d_in[4];
    const float* b_hh = (const float*)d_in[5];
    const float* W_fc = (const float*)d_in[6];
    const float* b_fc = (const float*)d_in[7];
    float* out = (float*)d_out;

    char* w = (char*)d_ws;
    __bf16* hb   = (__bf16*)w;  w += (size_t)N_NODES * H_C * 2;       // 16.78 MB
    float*  c    = (float*)w;   w += (size_t)N_NODES * H_C * 4;       // 33.55 MB
    __bf16* gx   = (__bf16*)w;  w += (size_t)N_LEAF0 * 1024 * 2;      // 33.55 MB
    __bf16* wihb = (__bf16*)w;  w += (size_t)4 * H_C * IN_C * 2;      // 1.05 MB
    __bf16* whhb = (__bf16*)w;  w += (size_t)4 * H_C * H_C * 2;       // 0.52 MB
    float*  part = (float*)w;                                          // 0.26 MB

    {
        const int n8i = (4 * H_C * IN_C) / 8;
        conv_bf16_kernel<<<(n8i + 255) / 256, 256, 0, stream>>>(W_ih, wihb, n8i);
        const int n8h = (4 * H_C * H_C) / 8;
        conv_bf16_kernel<<<(n8h + 255) / 256, 256, 0, stream>>>(W_hh, whhb, n8h);
    }

    bulk_xw<<<2048, 256, 0, stream>>>(x, wihb, b_ih, b_hh, hb, c, gx);

    {
        void* args[] = { (void*)&whhb, (void*)&b_ih, (void*)&b_hh,
                         (void*)&gx, (void*)&hb, (void*)&c };
        hipLaunchCooperativeKernel((const void*)levels_fused,
                                   dim3(512), dim3(256), args, 0, stream);
    }

    reduce_rows<<<256, 256, 0, stream>>>(hb, part);
    reduce_final<<<1, 256, 0, stream>>>(part, W_fc, b_fc, out);
}

// Round 5
// 455.652 us; speedup vs baseline: 2.5545x; 2.5545x over previous
//
#include <hip/hip_runtime.h>
#include <math.h>

// TreeLSTM, complete binary tree N = 2^15-1 (implicit: children(i)=2i+1,2i+2).
// Round 5: cooperative grid.sync abandoned (65us/sync measured). Back to
// per-level launches with a barrier-free level kernel:
//   mean_h @ W^T == [h_L | h_R] @ [0.5W | 0.5W]^T, and children rows are
//   ADJACENT in hb -> A rows are 512 contiguous bf16: direct global->VGPR
//   fragments, zero averaging VALU, zero K-loop barriers. 0.5*W_hh staged to
//   LDS once per kernel (64 KB). Bulk grid swizzled mt-major so the 8 slab
//   blocks of an m-tile are temporally adjacent (L3 serves x re-reads).

#define N_NODES 32767
#define N_LEAF0 16383
#define IN_C    512
#define H_C     256

typedef __bf16 bf16x8 __attribute__((ext_vector_type(8)));
typedef __bf16 bf16x4 __attribute__((ext_vector_type(4)));
typedef float  f32x4  __attribute__((ext_vector_type(4)));

__device__ __forceinline__ void gload_lds16(const void* g, void* l) {
    __builtin_amdgcn_global_load_lds(
        (const __attribute__((address_space(1))) unsigned int*)g,
        (__attribute__((address_space(3))) unsigned int*)l,
        16, 0, 0);
}

__device__ __forceinline__ float fast_rcp(float x) { return __builtin_amdgcn_rcpf(x); }
__device__ __forceinline__ float sigm(float x)     { return fast_rcp(1.f + __expf(-x)); }
__device__ __forceinline__ float tanh_fast(float x){ return 2.f * fast_rcp(1.f + __expf(-2.f * x)) - 1.f; }

// ---- fp32 -> bf16 converter with scale (weights only) ----
__global__ __launch_bounds__(256)
void conv_bf16_kernel(const float* __restrict__ src, __bf16* __restrict__ dst,
                      int n8, float scale)
{
    const int i = blockIdx.x * 256 + threadIdx.x;
    if (i < n8) {
        const float4* s4 = (const float4*)src;
        const float4 a = s4[2 * i];
        const float4 b = s4[2 * i + 1];
        bf16x8 o;
        o[0] = (__bf16)(scale * a.x); o[1] = (__bf16)(scale * a.y);
        o[2] = (__bf16)(scale * a.z); o[3] = (__bf16)(scale * a.w);
        o[4] = (__bf16)(scale * b.x); o[5] = (__bf16)(scale * b.y);
        o[6] = (__bf16)(scale * b.z); o[7] = (__bf16)(scale * b.w);
        *(bf16x8*)(dst + 8 * i) = o;
    }
}

// ---- bulk: acc = x @ W_ih^T for ALL nodes. Leaves: full cell. Internal: gx.
// grid = 2048 linear; cb = bx&7, mt = bx>>3: the 8 slab blocks of one m-tile
// are temporally adjacent -> x tile read once from HBM, L3 serves the rest.
__global__ __launch_bounds__(256)
void bulk_xw(const float* __restrict__ x,
             const __bf16* __restrict__ wih,
             const float* __restrict__ b_ih,
             const float* __restrict__ b_hh,
             __bf16* __restrict__ hb,
             float* __restrict__ c,
             __bf16* __restrict__ gx)
{
    __shared__ __bf16 As[128 * 32];
    __shared__ __bf16 Bs[128 * 32];

    const int t    = threadIdx.x;
    const int lane = t & 63;
    const int wv   = t >> 6;
    const int wm   = wv >> 1;
    const int wn   = wv & 1;
    const int quad = lane >> 4;
    const int l15  = lane & 15;
    const int bx   = blockIdx.x;
    const int cb   = bx & 7;
    const int m0   = (bx >> 3) * 128;

    f32x4 acc[4][4];
#pragma unroll
    for (int mi = 0; mi < 4; ++mi)
#pragma unroll
        for (int ni = 0; ni < 4; ++ni) acc[mi][ni] = (f32x4)0.f;

    for (int k0 = 0; k0 < IN_C; k0 += 32) {
#pragma unroll
        for (int e = 0; e < 2; ++e) {
            const int chunk = wv * 2 + e;
            const int nl    = chunk * 16 + (lane >> 2);
            const int q     = (nl >> 4) & 3;
            const int cc    = (nl & 15) + ((nl >> 6) << 4);
            const int grow  = q * H_C + cb * 32 + cc;
            const void* g = (const char*)(wih + grow * IN_C + k0) + (lane & 3) * 16;
            gload_lds16(g, (char*)Bs + chunk * 1024);
        }
        {
            const int row  = t >> 1;
            const int kh   = (t & 1) * 16;
            const int node = min(m0 + row, N_NODES - 1);
            const float4* xs = (const float4*)(x + (size_t)node * IN_C + k0 + kh);
            const float4 v0 = xs[0], v1 = xs[1], v2 = xs[2], v3 = xs[3];
            bf16x8 o0, o1;
            o0[0] = (__bf16)v0.x; o0[1] = (__bf16)v0.y; o0[2] = (__bf16)v0.z; o0[3] = (__bf16)v0.w;
            o0[4] = (__bf16)v1.x; o0[5] = (__bf16)v1.y; o0[6] = (__bf16)v1.z; o0[7] = (__bf16)v1.w;
            o1[0] = (__bf16)v2.x; o1[1] = (__bf16)v2.y; o1[2] = (__bf16)v2.z; o1[3] = (__bf16)v2.w;
            o1[4] = (__bf16)v3.x; o1[5] = (__bf16)v3.y; o1[6] = (__bf16)v3.z; o1[7] = (__bf16)v3.w;
            bf16x8* dst = (bf16x8*)(As + row * 32 + kh);
            dst[0] = o0;
            dst[1] = o1;
        }
        __syncthreads();
        bf16x8 af[4], bfr[4];
#pragma unroll
        for (int mi = 0; mi < 4; ++mi)
            af[mi] = *(const bf16x8*)(As + (wm * 64 + mi * 16 + l15) * 32 + quad * 8);
#pragma unroll
        for (int ni = 0; ni < 4; ++ni)
            bfr[ni] = *(const bf16x8*)(Bs + (wn * 64 + ni * 16 + l15) * 32 + quad * 8);
#pragma unroll
        for (int mi = 0; mi < 4; ++mi)
#pragma unroll
            for (int ni = 0; ni < 4; ++ni)
                acc[mi][ni] = __builtin_amdgcn_mfma_f32_16x16x32_bf16(
                    af[mi], bfr[ni], acc[mi][ni], 0, 0, 0);
        __syncthreads();
    }

    const int CH = cb * 32 + wn * 16 + l15;
    float bs[4];
#pragma unroll
    for (int q = 0; q < 4; ++q) bs[q] = b_ih[q * H_C + CH] + b_hh[q * H_C + CH];

#pragma unroll
    for (int mi = 0; mi < 4; ++mi) {
#pragma unroll
        for (int r = 0; r < 4; ++r) {
            const int m = m0 + wm * 64 + mi * 16 + quad * 4 + r;
            if (m >= N_NODES) continue;
            if (m >= N_LEAF0) {
                const float gi = sigm(acc[mi][0][r] + bs[0]);
                const float gg = tanh_fast(acc[mi][2][r] + bs[2]);
                const float go = sigm(acc[mi][3][r] + bs[3]);
                const float cn = gi * gg;
                const float hn = go * tanh_fast(cn);
                c[(size_t)m * H_C + CH] = cn;
                hb[(size_t)m * H_C + CH] = (__bf16)hn;
            } else {
                bf16x4 g4;
#pragma unroll
                for (int q = 0; q < 4; ++q) g4[q] = (__bf16)acc[mi][q][r];
                *(bf16x4*)(gx + (size_t)m * 1024 + CH * 4) = g4;
            }
        }
    }
}

// ---- per-level kernel: gates = gx + [h_L|h_R] @ [0.5W|0.5W]^T (K=512),
// A fragments direct global->VGPR (children rows are adjacent -> contiguous),
// B (=0.5*W_hh) staged to LDS once; ONE barrier per kernel, none in K-loop. ----
__global__ __launch_bounds__(256)
void level_hw(const __bf16* __restrict__ whh2,   // 0.5*W_hh, bf16
              const float* __restrict__ b_ih,
              const float* __restrict__ b_hh,
              const __bf16* __restrict__ gx,
              __bf16* __restrict__ hb,
              float* __restrict__ c,
              int lo, int n)
{
    __shared__ __bf16 Bfull[8 * 128 * 32];   // 64 KB: whole K=256 0.5*W_hh slab

    const int t    = threadIdx.x;
    const int lane = t & 63;
    const int wv   = t >> 6;
    const int wm   = wv >> 1;
    const int wn   = wv & 1;
    const int quad = lane >> 4;
    const int l15  = lane & 15;
    const int bx   = blockIdx.x;
    const int cb   = bx & 7;
    const int m0   = (bx >> 3) * 128;

    // ---- stage 0.5*W_hh slab once ----
#pragma unroll
    for (int kc = 0; kc < 8; ++kc) {
#pragma unroll
        for (int e = 0; e < 2; ++e) {
            const int chunk = wv * 2 + e;
            const int nl    = chunk * 16 + (lane >> 2);
            const int q     = (nl >> 4) & 3;
            const int cc    = (nl & 15) + ((nl >> 6) << 4);
            const int grow  = q * H_C + cb * 32 + cc;
            const void* g = (const char*)(whh2 + grow * H_C + kc * 32) + (lane & 3) * 16;
            gload_lds16(g, (char*)Bfull + kc * 8192 + chunk * 1024);
        }
    }
    __syncthreads();

    f32x4 acc[4][4];
#pragma unroll
    for (int mi = 0; mi < 4; ++mi)
#pragma unroll
        for (int ni = 0; ni < 4; ++ni) acc[mi][ni] = (f32x4)0.f;

    // A row m = 512 contiguous bf16 at hb + (2*node+1)*256  (children adjacent)
    size_t abase[4];
#pragma unroll
    for (int mi = 0; mi < 4; ++mi) {
        const int node = lo + m0 + wm * 64 + mi * 16 + l15;
        abase[mi] = (size_t)(2 * node + 1) * H_C;
    }

#pragma unroll
    for (int kc = 0; kc < 16; ++kc) {
        bf16x8 af[4], bfr[4];
#pragma unroll
        for (int mi = 0; mi < 4; ++mi)
            af[mi] = *(const bf16x8*)(hb + abase[mi] + kc * 32 + quad * 8);
#pragma unroll
        for (int ni = 0; ni < 4; ++ni)
            bfr[ni] = *(const bf16x8*)(Bfull + (kc & 7) * 4096 +
                                       (wn * 64 + ni * 16 + l15) * 32 + quad * 8);
#pragma unroll
        for (int mi = 0; mi < 4; ++mi)
#pragma unroll
            for (int ni = 0; ni < 4; ++ni)
                acc[mi][ni] = __builtin_amdgcn_mfma_f32_16x16x32_bf16(
                    af[mi], bfr[ni], acc[mi][ni], 0, 0, 0);
    }

    const int CH = cb * 32 + wn * 16 + l15;
    const float bs0 = b_ih[0 * H_C + CH] + b_hh[0 * H_C + CH];
    const float bs1 = b_ih[1 * H_C + CH] + b_hh[1 * H_C + CH];
    const float bs2 = b_ih[2 * H_C + CH] + b_hh[2 * H_C + CH];
    const float bs3 = b_ih[3 * H_C + CH] + b_hh[3 * H_C + CH];

#pragma unroll
    for (int mi = 0; mi < 4; ++mi) {
#pragma unroll
        for (int r = 0; r < 4; ++r) {
            const int m = m0 + wm * 64 + mi * 16 + quad * 4 + r;
            if (m < n) {
                const int node = lo + m;
                const bf16x4 g4 = *(const bf16x4*)(gx + (size_t)node * 1024 + CH * 4);
                const float gi = sigm(acc[mi][0][r] + (float)g4[0] + bs0);
                const float gf = sigm(acc[mi][1][r] + (float)g4[1] + bs1);
                const float gt = tanh_fast(acc[mi][2][r] + (float)g4[2] + bs2);
                const float go = sigm(acc[mi][3][r] + (float)g4[3] + bs3);
                const float mc = 0.5f * (c[(size_t)(2 * node + 1) * H_C + CH] +
                                         c[(size_t)(2 * node + 2) * H_C + CH]);
                const float cn = gf * mc + gi * gt;
                const float hn = go * tanh_fast(cn);
                c[(size_t)node * H_C + CH] = cn;
                hb[(size_t)node * H_C + CH] = (__bf16)hn;
            }
        }
    }
}

// ---- pooled mean + fc ----
__global__ __launch_bounds__(256)
void reduce_rows(const __bf16* __restrict__ hb, float* __restrict__ part)
{
    const int tcol = threadIdx.x;
    const int b = blockIdx.x;
    float s = 0.f;
    for (int r = 0; r < 128; ++r) {
        const int row = b * 128 + r;
        if (row < N_NODES) s += (float)hb[(size_t)row * H_C + tcol];
    }
    part[b * H_C + tcol] = s;
}

__global__ __launch_bounds__(256)
void reduce_final(const float* __restrict__ part,
                  const float* __restrict__ W_fc,
                  const float* __restrict__ b_fc,
                  float* __restrict__ out)
{
    __shared__ float sm[256];
    const int t = threadIdx.x;
    float s = 0.f;
    for (int j = 0; j < 256; ++j) s += part[j * H_C + t];
    s = s * (1.0f / (float)N_NODES) * W_fc[t];
    sm[t] = s;
    __syncthreads();
    for (int st = 128; st > 0; st >>= 1) {
        if (t < st) sm[t] += sm[t + st];
        __syncthreads();
    }
    if (t == 0) out[0] = sm[0] + b_fc[0];
}

extern "C" void kernel_launch(void* const* d_in, const int* in_sizes, int n_in,
                              void* d_out, int out_size, void* d_ws, size_t ws_size,
                              hipStream_t stream)
{
    const float* x    = (const float*)d_in[0];
    const float* W_ih = (const float*)d_in[2];
    const float* W_hh = (const float*)d_in[3];
    const float* b_ih = (const float*)d_in[4];
    const float* b_hh = (const float*)d_in[5];
    const float* W_fc = (const float*)d_in[6];
    const float* b_fc = (const float*)d_in[7];
    float* out = (float*)d_out;

    char* w = (char*)d_ws;
    __bf16* hb   = (__bf16*)w;  w += (size_t)N_NODES * H_C * 2;       // 16.78 MB
    float*  c    = (float*)w;   w += (size_t)N_NODES * H_C * 4;       // 33.55 MB
    __bf16* gx   = (__bf16*)w;  w += (size_t)N_LEAF0 * 1024 * 2;      // 33.55 MB
    __bf16* wihb = (__bf16*)w;  w += (size_t)4 * H_C * IN_C * 2;      // 1.05 MB
    __bf16* whh2 = (__bf16*)w;  w += (size_t)4 * H_C * H_C * 2;       // 0.52 MB
    float*  part = (float*)w;                                          // 0.26 MB

    {
        const int n8i = (4 * H_C * IN_C) / 8;
        conv_bf16_kernel<<<(n8i + 255) / 256, 256, 0, stream>>>(W_ih, wihb, n8i, 1.0f);
        const int n8h = (4 * H_C * H_C) / 8;
        conv_bf16_kernel<<<(n8h + 255) / 256, 256, 0, stream>>>(W_hh, whh2, n8h, 0.5f);
    }

    bulk_xw<<<2048, 256, 0, stream>>>(x, wihb, b_ih, b_hh, hb, c, gx);

    for (int d = 13; d >= 0; --d) {
        const int n  = 1 << d;
        const int lo = n - 1;
        const int nm = (n + 127) / 128;
        level_hw<<<8 * nm, 256, 0, stream>>>(whh2, b_ih, b_hh, gx, hb, c, lo, n);
    }

    reduce_rows<<<256, 256, 0, stream>>>(hb, part);
    reduce_final<<<1, 256, 0, stream>>>(part, W_fc, b_fc, out);
}